// Round 8
// baseline (488.695 us; speedup 1.0000x reference)
//
#include <hip/hip_runtime.h>
#include <math.h>

// Problem constants
#define B_   2
#define LTOT   8192
#define LCACHE 6144
#define LNEW   2048

#define QSCALE (0.125f * 1.44269504088896f)   // 1/sqrt(64) * log2(e)

typedef __attribute__((ext_vector_type(8))) short bf16x8;
typedef __attribute__((ext_vector_type(4))) float f32x4;

__device__ __forceinline__ ushort f2bf(float f) {             // RTN f32->bf16
    unsigned u = __float_as_uint(f);
    return (ushort)((u + 0x7fffu + ((u >> 16) & 1u)) >> 16);
}
__device__ __forceinline__ void split_hilo(float v, ushort& h, ushort& l) {
    h = f2bf(v);
    l = f2bf(v - __uint_as_float((unsigned)h << 16));
}

// ---------------------------------------------------------------------------
// Layouts (identical to round 6, all verified):
// GEMM frag: flat = R*8192 + kk*512 + lane*8 + j
//            holds T[row=R*16+(lane&15)][col=kk*32+(lane>>4)*8+j]
// K swz:     flat = T*2048 + st*1024 + h*512 + lane*8 + j
//            holds K[key=T*32+st*4+(lr&3)+(lr>>2)*8][e=h*32+lg*8+j]
// V^T swz:   flat = T*2048 + dt*512 + lane*8 + j
//            holds V[key=T*32+lg*8+j][d=dt*16+lr]
// ---------------------------------------------------------------------------

__device__ __forceinline__ void convert_slot(
    const float* __restrict__ src, ushort* __restrict__ dh, ushort* __restrict__ dl, int slot)
{
    const int R = slot >> 10, kk = (slot >> 6) & 15, ln = slot & 63;
    const int row = R * 16 + (ln & 15), col = kk * 32 + (ln >> 4) * 8;
    const float4 a  = *reinterpret_cast<const float4*>(src + row * 512 + col);
    const float4 b4 = *reinterpret_cast<const float4*>(src + row * 512 + col + 4);
    ushort4 h0, l0, h1, l1;
    split_hilo(a.x,  h0.x, l0.x); split_hilo(a.y,  h0.y, l0.y);
    split_hilo(a.z,  h0.z, l0.z); split_hilo(a.w,  h0.w, l0.w);
    split_hilo(b4.x, h1.x, l1.x); split_hilo(b4.y, h1.y, l1.y);
    split_hilo(b4.z, h1.z, l1.z); split_hilo(b4.w, h1.w, l1.w);
    *reinterpret_cast<ushort4*>(dh + slot * 8)     = h0;
    *reinterpret_cast<ushort4*>(dh + slot * 8 + 4) = h1;
    *reinterpret_cast<ushort4*>(dl + slot * 8)     = l0;
    *reinterpret_cast<ushort4*>(dl + slot * 8 + 4) = l1;
}

__device__ __forceinline__ void kcache_slot(
    const float* __restrict__ Kc, ushort* __restrict__ Khi, ushort* __restrict__ Klo,
    int b, int slot)
{
    const int key = slot >> 3, g = slot & 7;
    const int h = g >> 2, lg = g & 3;
    const float* src = Kc + ((size_t)b * LCACHE + key) * 64 + g * 8;
    const float4 a  = *reinterpret_cast<const float4*>(src);
    const float4 b4 = *reinterpret_cast<const float4*>(src + 4);
    const int T = key >> 5, r = key & 31;
    const int lr = ((r >> 3) << 2) | (r & 3), st = (r >> 2) & 1;
    const size_t dst = (size_t)b * 524288 + T * 2048 + st * 1024
                     + h * 512 + (((size_t)lg << 4 | lr)) * 8;
    ushort4 h0, l0, h1, l1;
    split_hilo(a.x,  h0.x, l0.x); split_hilo(a.y,  h0.y, l0.y);
    split_hilo(a.z,  h0.z, l0.z); split_hilo(a.w,  h0.w, l0.w);
    split_hilo(b4.x, h1.x, l1.x); split_hilo(b4.y, h1.y, l1.y);
    split_hilo(b4.z, h1.z, l1.z); split_hilo(b4.w, h1.w, l1.w);
    *reinterpret_cast<ushort4*>(Khi + dst)     = h0;
    *reinterpret_cast<ushort4*>(Khi + dst + 4) = h1;
    *reinterpret_cast<ushort4*>(Klo + dst)     = l0;
    *reinterpret_cast<ushort4*>(Klo + dst + 4) = l1;
}

// 8-wave MFMA NT GEMM tile: 64x64 block tile, wave stripe 16(m) x 32(n).
__device__ __forceinline__ void proj8(
    const ushort* __restrict__ AhF, const ushort* __restrict__ AlF,
    const ushort* __restrict__ BhF, const ushort* __restrict__ BlF,
    const float* __restrict__ bias, const int mode, const int bxp, const int byp,
    ushort* __restrict__ d1, ushort* __restrict__ d2, float* __restrict__ df)
{
    const int tid = threadIdx.x;
    const int wv = tid >> 6, lane = tid & 63;
    const int lr = lane & 15, lg = lane >> 4;
    const int m0 = byp * 64 + (wv & 3) * 16;   // token stripe
    const int n0 = bxp * 64 + (wv >> 2) * 32;  // output-dim half
    const int mT = m0 >> 4, nT = n0 >> 4;

    f32x4 acc[2];
    acc[0] = (f32x4){0.f, 0.f, 0.f, 0.f};
    acc[1] = (f32x4){0.f, 0.f, 0.f, 0.f};

    const ushort* Ah = AhF + (size_t)nT * 8192 + lane * 8;
    const ushort* Al = AlF + (size_t)nT * 8192 + lane * 8;
    const ushort* Bh = BhF + (size_t)mT * 8192 + lane * 8;
    const ushort* Bl = BlF + (size_t)mT * 8192 + lane * 8;

#pragma unroll 4
    for (int kk = 0; kk < 16; ++kk) {
        bf16x8 ah[2], al[2], bh, bl;
#pragma unroll
        for (int t = 0; t < 2; ++t) {
            ah[t] = *reinterpret_cast<const bf16x8*>(Ah + t * 8192 + kk * 512);
            al[t] = *reinterpret_cast<const bf16x8*>(Al + t * 8192 + kk * 512);
        }
        bh = *reinterpret_cast<const bf16x8*>(Bh + kk * 512);
        bl = *reinterpret_cast<const bf16x8*>(Bl + kk * 512);
        __builtin_amdgcn_s_setprio(1);
#pragma unroll
        for (int ni = 0; ni < 2; ++ni) {
            acc[ni] = __builtin_amdgcn_mfma_f32_16x16x32_bf16(ah[ni], bh, acc[ni], 0, 0, 0);
            acc[ni] = __builtin_amdgcn_mfma_f32_16x16x32_bf16(ah[ni], bl, acc[ni], 0, 0, 0);
            acc[ni] = __builtin_amdgcn_mfma_f32_16x16x32_bf16(al[ni], bh, acc[ni], 0, 0, 0);
        }
        __builtin_amdgcn_s_setprio(0);
    }

#pragma unroll
    for (int ni = 0; ni < 2; ++ni) {
        const int tok = m0 + lr;
        const int e   = n0 + ni * 16 + lg * 4;
        const float4 bb4 = *reinterpret_cast<const float4*>(&bias[e]);
        float v0 = acc[ni].x + bb4.x, v1 = acc[ni].y + bb4.y;
        float v2 = acc[ni].z + bb4.z, v3 = acc[ni].w + bb4.w;
        const int bb = tok >> 8, s = tok & 255;
        if (mode == 0) {
            v0 *= QSCALE; v1 *= QSCALE; v2 *= QSCALE; v3 *= QSCALE;
            ushort4 h, l;
            split_hilo(v0, h.x, l.x); split_hilo(v1, h.y, l.y);
            split_hilo(v2, h.z, l.z); split_hilo(v3, h.w, l.w);
            const size_t off = (size_t)bb * 131072 + s * 512 + e;
            *reinterpret_cast<ushort4*>(d1 + off) = h;
            *reinterpret_cast<ushort4*>(d2 + off) = l;
        } else if (mode == 1) {
            const int key = LCACHE + s * 8 + (e >> 6);
            const int d0 = e & 63;
            const int T = key >> 5, r = key & 31;
            const int klr = ((r >> 3) << 2) | (r & 3), st = (r >> 2) & 1;
            const int h = d0 >> 5, lg2 = (d0 >> 3) & 3, j0 = d0 & 7;
            const size_t dst = (size_t)bb * 524288 + T * 2048 + st * 1024
                             + h * 512 + ((lg2 << 4) | klr) * 8 + j0;
            ushort4 hh, ll;
            split_hilo(v0, hh.x, ll.x); split_hilo(v1, hh.y, ll.y);
            split_hilo(v2, hh.z, ll.z); split_hilo(v3, hh.w, ll.w);
            *reinterpret_cast<ushort4*>(d1 + dst) = hh;
            *reinterpret_cast<ushort4*>(d2 + dst) = ll;
        } else if (mode == 2) {
            const int key = LCACHE + s * 8 + (e >> 6);
            const int Tv = key >> 5;
            const int lg3 = (key & 31) >> 3, j = key & 7;
            const float vals[4] = {v0, v1, v2, v3};
#pragma unroll
            for (int c = 0; c < 4; ++c) {
                const int d = (e & 63) + c;
                const int dt = d >> 4, vlr = d & 15;
                d1[(size_t)bb * 524288 + Tv * 2048 + dt * 512
                   + ((lg3 << 4) | vlr) * 8 + j] = f2bf(vals[c]);
            }
        } else {
            float4 o; o.x = v0; o.y = v1; o.z = v2; o.w = v3;
            *reinterpret_cast<float4*>(df + (size_t)tok * 512 + e) = o;
        }
    }
}

// attention macros: r6 swizzled ALOAD, r4-verified single-(m,l) COMPUTE
#define ALOAD(kf, lf, vf, t) do {                                                   \
    _Pragma("unroll")                                                               \
    for (int st = 0; st < 2; ++st) {                                                \
        _Pragma("unroll")                                                           \
        for (int h = 0; h < 2; ++h) {                                               \
            kf[st][h] = *reinterpret_cast<const bf16x8*>(kh_p + (t) * 2048 + st * 1024 + h * 512); \
            lf[st][h] = *reinterpret_cast<const bf16x8*>(kl_p + (t) * 2048 + st * 1024 + h * 512); \
        }                                                                           \
    }                                                                               \
    _Pragma("unroll")                                                               \
    for (int dt = 0; dt < 4; ++dt)                                                  \
        vf[dt] = *reinterpret_cast<const bf16x8*>(vt_p + (t) * 2048 + dt * 512);    \
} while (0)

#define ACOMP(kf, lf, vf) do {                                                      \
    f32x4 s0 = {0.f,0.f,0.f,0.f}, s1 = {0.f,0.f,0.f,0.f};                           \
    __builtin_amdgcn_s_setprio(1);                                                  \
    _Pragma("unroll")                                                               \
    for (int h = 0; h < 2; ++h) {                                                   \
        s0 = __builtin_amdgcn_mfma_f32_16x16x32_bf16(kf[0][h], qh[h], s0, 0, 0, 0); \
        s0 = __builtin_amdgcn_mfma_f32_16x16x32_bf16(kf[0][h], ql[h], s0, 0, 0, 0); \
        s0 = __builtin_amdgcn_mfma_f32_16x16x32_bf16(lf[0][h], qh[h], s0, 0, 0, 0); \
        s1 = __builtin_amdgcn_mfma_f32_16x16x32_bf16(kf[1][h], qh[h], s1, 0, 0, 0); \
        s1 = __builtin_amdgcn_mfma_f32_16x16x32_bf16(kf[1][h], ql[h], s1, 0, 0, 0); \
        s1 = __builtin_amdgcn_mfma_f32_16x16x32_bf16(lf[1][h], qh[h], s1, 0, 0, 0); \
    }                                                                               \
    __builtin_amdgcn_s_setprio(0);                                                  \
    float tm = fmaxf(fmaxf(fmaxf(s0.x, s0.y), fmaxf(s0.z, s0.w)),                   \
                     fmaxf(fmaxf(s1.x, s1.y), fmaxf(s1.z, s1.w)));                  \
    tm = fmaxf(tm, __shfl_xor(tm, 16));                                             \
    tm = fmaxf(tm, __shfl_xor(tm, 32));                                             \
    const float mn = fmaxf(m, tm);                                                  \
    const float corr = __builtin_exp2f(m - mn);                                     \
    float p[8];                                                                     \
    p[0] = __builtin_exp2f(s0.x - mn); p[1] = __builtin_exp2f(s0.y - mn);           \
    p[2] = __builtin_exp2f(s0.z - mn); p[3] = __builtin_exp2f(s0.w - mn);           \
    p[4] = __builtin_exp2f(s1.x - mn); p[5] = __builtin_exp2f(s1.y - mn);           \
    p[6] = __builtin_exp2f(s1.z - mn); p[7] = __builtin_exp2f(s1.w - mn);           \
    float ps = ((p[0]+p[1]) + (p[2]+p[3])) + ((p[4]+p[5]) + (p[6]+p[7]));           \
    ps += __shfl_xor(ps, 16);                                                       \
    ps += __shfl_xor(ps, 32);                                                       \
    l = l * corr + ps; m = mn;                                                      \
    union { bf16x8 v; ushort u[8]; } pf;                                            \
    _Pragma("unroll")                                                               \
    for (int j = 0; j < 8; ++j) pf.u[j] = f2bf(p[j]);                               \
    __builtin_amdgcn_s_setprio(1);                                                  \
    _Pragma("unroll")                                                               \
    for (int dt = 0; dt < 4; ++dt) {                                                \
        f32x4 a = acc[dt];                                                          \
        a.x *= corr; a.y *= corr; a.z *= corr; a.w *= corr;                         \
        acc[dt] = __builtin_amdgcn_mfma_f32_16x16x32_bf16(vf[dt], pf.v, a, 0, 0, 0);\
    }                                                                               \
    __builtin_amdgcn_s_setprio(0);                                                  \
} while (0)

// ---------------------------------------------------------------------------
// Software grid barrier (256 blocks, init-tolerant via magic epochs; ws is
// re-poisoned 0xAA before every timed launch so cells never retain epochs).
// ---------------------------------------------------------------------------
__device__ __forceinline__ void gridbarrier(uint* flags, uint* rel, int bar, int bid)
{
    __syncthreads();
    __threadfence();
    const uint ep = 0x1357A001u + (uint)bar;
    uint* f = flags + bar * 256;
    if (threadIdx.x == 0)
        __hip_atomic_store(f + bid, ep, __ATOMIC_RELEASE, __HIP_MEMORY_SCOPE_AGENT);
    if (bid == 0) {
        if (threadIdx.x < 256) {
            while (__hip_atomic_load(f + threadIdx.x, __ATOMIC_ACQUIRE,
                                     __HIP_MEMORY_SCOPE_AGENT) != ep)
                __builtin_amdgcn_s_sleep(1);
        }
        __syncthreads();
        if (threadIdx.x == 0)
            __hip_atomic_store(rel + bar, ep, __ATOMIC_RELEASE, __HIP_MEMORY_SCOPE_AGENT);
    }
    if (threadIdx.x == 0) {
        while (__hip_atomic_load(rel + bar, __ATOMIC_ACQUIRE,
                                 __HIP_MEMORY_SCOPE_AGENT) != ep)
            __builtin_amdgcn_s_sleep(1);
    }
    __syncthreads();
    __threadfence();
}

// ---------------------------------------------------------------------------
// fused_all: 256 blocks x 512 threads (8 waves), plain launch.
// P1 prep -> P2 proj_qkv -> P3 attn (full-L, writes Ao) -> P4 proj_o.
// ---------------------------------------------------------------------------
__global__ __launch_bounds__(512, 2) void fused_all(
    const float* __restrict__ x,  const float* __restrict__ Kc,
    const float* __restrict__ Vc,
    const float* __restrict__ Wq, const float* __restrict__ bq,
    const float* __restrict__ Wk, const float* __restrict__ bk,
    const float* __restrict__ Wv, const float* __restrict__ bv,
    const float* __restrict__ Wo, const float* __restrict__ bo,
    float* __restrict__ out,
    ushort* __restrict__ Khi, ushort* __restrict__ Klo, ushort* __restrict__ VtS,
    ushort* __restrict__ Qhi, ushort* __restrict__ Qlo,
    ushort* __restrict__ xh,  ushort* __restrict__ xl,
    ushort* __restrict__ Wqh, ushort* __restrict__ Wql,
    ushort* __restrict__ Wkh, ushort* __restrict__ Wkl,
    ushort* __restrict__ Wvh, ushort* __restrict__ Wvl,
    ushort* __restrict__ Woh, ushort* __restrict__ Wol,
    ushort* __restrict__ Aoh, ushort* __restrict__ Aol,
    uint* __restrict__ gflags, uint* __restrict__ grel)
{
    __shared__ union SM {
        ushort sT[64][68];
        struct { float sAcc[8][16][68]; float sM[8][16]; float sL[8][16]; } a;
    } sm;

    const int bid = blockIdx.x, tid = threadIdx.x;
    const int gid = bid * 512 + tid;            // 0..131071

    // ---------------- P1: prep ---------------------------------------------
    {
        {   // (a) {x,Wq,Wk,Wv}: one slot/thread; Wo: gid<32768
            const int z = gid >> 15, slot = gid & 32767;
            const float* src; ushort* dh; ushort* dl;
            if (z == 0)      { src = x;  dh = xh;  dl = xl;  }
            else if (z == 1) { src = Wq; dh = Wqh; dl = Wql; }
            else if (z == 2) { src = Wk; dh = Wkh; dl = Wkl; }
            else             { src = Wv; dh = Wvh; dl = Wvl; }
            convert_slot(src, dh, dl, slot);
            if (gid < 32768) convert_slot(Wo, Woh, Wol, gid);
        }
        // (b) K cache: 98304 slots
        if (gid < 98304) {
            const int b = gid >= 49152 ? 1 : 0;
            kcache_slot(Kc, Khi, Klo, b, gid - b * 49152);
        }
        // (c) V cache: 192 tiles of 64 keys, blocks 0..191
        if (bid < 192) {
            const int b = bid / 96, kt = bid % 96;
            const int key0 = kt * 64;
#pragma unroll
            for (int it = 0; it < 2; ++it) {
                const int id = it * 512 + tid;              // 0..1023
                const int row = id >> 4, c4 = (id & 15) << 2;
                const float4 v = *reinterpret_cast<const float4*>(
                    &Vc[((size_t)b * LCACHE + key0 + row) * 64 + c4]);
                sm.sT[c4+0][row] = f2bf(v.x); sm.sT[c4+1][row] = f2bf(v.y);
                sm.sT[c4+2][row] = f2bf(v.z); sm.sT[c4+3][row] = f2bf(v.w);
            }
            __syncthreads();
            {
                const int s = tid;                          // 0..511
                const int Tl = s >> 8, dt = (s >> 6) & 3, ln = s & 63;
                const int lr2 = ln & 15, lg2 = ln >> 4;
                const int kb = Tl * 32 + lg2 * 8;
                ushort4 o0, o1;
                o0.x = sm.sT[dt*16+lr2][kb+0]; o0.y = sm.sT[dt*16+lr2][kb+1];
                o0.z = sm.sT[dt*16+lr2][kb+2]; o0.w = sm.sT[dt*16+lr2][kb+3];
                o1.x = sm.sT[dt*16+lr2][kb+4]; o1.y = sm.sT[dt*16+lr2][kb+5];
                o1.z = sm.sT[dt*16+lr2][kb+6]; o1.w = sm.sT[dt*16+lr2][kb+7];
                const size_t dst = (size_t)b * 524288 + ((key0 >> 5) + Tl) * 2048
                                 + dt * 512 + ln * 8;
                *reinterpret_cast<ushort4*>(VtS + dst)     = o0;
                *reinterpret_cast<ushort4*>(VtS + dst + 4) = o1;
            }
        }
    }
    gridbarrier(gflags, grel, 0, bid);

    // ---------------- P2: QKV projections (blocks 0..191) ------------------
    if (bid < 192) {
        const int z = bid >> 6, idx = bid & 63;
        const int bxp = idx & 7, byp = idx >> 3;
        if (z == 0)      proj8(Wqh, Wql, xh, xl, bq, 0, bxp, byp, Qhi, Qlo, nullptr);
        else if (z == 1) proj8(Wkh, Wkl, xh, xl, bk, 1, bxp, byp, Khi, Klo, nullptr);
        else             proj8(Wvh, Wvl, xh, xl, bv, 2, bxp, byp, VtS, nullptr, nullptr);
    }
    gridbarrier(gflags, grel, 1, bid);

    // ---------------- P3: attn, full L per block, writes Ao -----------------
    {
        const int wv = tid >> 6, lane = tid & 63;
        const int lr = lane & 15, lg = lane >> 4;
        const int qb = bid & 127, b = bid >> 7;   // 16 q-rows/block

        bf16x8 qh[2], ql[2];
        {
            const int qrow0 = b * 2048 + qb * 16 + lr;
#pragma unroll
            for (int h = 0; h < 2; ++h) {
                const int off = qrow0 * 64 + h * 32 + lg * 8;
                qh[h] = *reinterpret_cast<const bf16x8*>(Qhi + off);
                ql[h] = *reinterpret_cast<const bf16x8*>(Qlo + off);
            }
        }

        const int T0 = wv * 32;                   // 32 tiles of 32 keys/wave
        const ushort* kh_p = Khi + (size_t)b * 524288 + (size_t)T0 * 2048 + lane * 8;
        const ushort* kl_p = Klo + (size_t)b * 524288 + (size_t)T0 * 2048 + lane * 8;
        const ushort* vt_p = VtS + (size_t)b * 524288 + (size_t)T0 * 2048 + lane * 8;

        f32x4 acc[4];
#pragma unroll
        for (int dt = 0; dt < 4; ++dt) acc[dt] = (f32x4){0.f, 0.f, 0.f, 0.f};
        float m = -INFINITY, l = 0.f;

        bf16x8 kfA[2][2], lfA[2][2], vfA[4];
        bf16x8 kfB[2][2], lfB[2][2], vfB[4];

        ALOAD(kfA, lfA, vfA, 0);
        for (int tt = 0; tt < 16; ++tt) {         // 32 tiles, 2 per iter
            ALOAD(kfB, lfB, vfB, 2 * tt + 1);
            ACOMP(kfA, lfA, vfA);
            if (tt < 15) ALOAD(kfA, lfA, vfA, 2 * tt + 2);
            ACOMP(kfB, lfB, vfB);
        }

        // per-wave partials -> LDS (C/D: col=lane&15 -> qrow, rows -> dims)
#pragma unroll
        for (int dt = 0; dt < 4; ++dt) {
            float4 o; o.x = acc[dt].x; o.y = acc[dt].y; o.z = acc[dt].z; o.w = acc[dt].w;
            *reinterpret_cast<float4*>(&sm.a.sAcc[wv][lr][dt * 16 + lg * 4]) = o;
        }
        if (lg == 0) { sm.a.sM[wv][lr] = m; sm.a.sL[wv][lr] = l; }
        __syncthreads();

        // merge 8 waves; write Ao (GEMM-frag hi/lo) directly
        {
            const int row = tid >> 5, d0 = (tid & 31) * 2;
            float ms = -INFINITY;
#pragma unroll
            for (int w = 0; w < 8; ++w) ms = fmaxf(ms, sm.a.sM[w][row]);
            float den = 0.f, n0 = 0.f, n1 = 0.f;
#pragma unroll
            for (int w = 0; w < 8; ++w) {
                const float e = __builtin_exp2f(sm.a.sM[w][row] - ms);
                den = fmaf(sm.a.sL[w][row], e, den);
                const float2 a = *reinterpret_cast<const float2*>(&sm.a.sAcc[w][row][d0]);
                n0 = fmaf(a.x, e, n0);
                n1 = fmaf(a.y, e, n1);
            }
            const float inv = 1.0f / den;
            const float v0 = n0 * inv, v1 = n1 * inv;
            const int row_g = b * 2048 + qb * 16 + row;
            const int qr = row_g & 2047;
            const int tok = b * 256 + (qr >> 3);
            const int e_  = (qr & 7) * 64 + d0;
            const int R = tok >> 4, lrr = tok & 15, kk = e_ >> 5, lgg = (e_ >> 3) & 3;
            const size_t dst = (size_t)R * 8192 + kk * 512 + ((lgg << 4) | lrr) * 8 + (d0 & 7);
            ushort h0, l0u, h1, l1u;
            split_hilo(v0, h0, l0u); split_hilo(v1, h1, l1u);
            ushort2 ho; ho.x = h0; ho.y = h1;
            ushort2 lo; lo.x = l0u; lo.y = l1u;
            *reinterpret_cast<ushort2*>(Aoh + dst) = ho;
            *reinterpret_cast<ushort2*>(Aol + dst) = lo;
        }
    }
    gridbarrier(gflags, grel, 2, bid);

    // ---------------- P4: output projection (blocks 0..63) ------------------
    if (bid < 64) {
        const int bxp = bid & 7, byp = bid >> 3;
        proj8(Woh, Wol, Aoh, Aol, bo, 3, bxp, byp, nullptr, nullptr, out);
    }
}

// ---------------------------------------------------------------------------
extern "C" void kernel_launch(void* const* d_in, const int* in_sizes, int n_in,
                              void* d_out, int out_size, void* d_ws, size_t ws_size,
                              hipStream_t stream)
{
    const float* x  = (const float*)d_in[0];
    const float* kc = (const float*)d_in[1];
    const float* vc = (const float*)d_in[2];
    const float* Wq = (const float*)d_in[3];
    const float* bq = (const float*)d_in[4];
    const float* Wk = (const float*)d_in[5];
    const float* bk = (const float*)d_in[6];
    const float* Wv = (const float*)d_in[7];
    const float* bv = (const float*)d_in[8];
    const float* Wo = (const float*)d_in[9];
    const float* bo = (const float*)d_in[10];
    float* out = (float*)d_out;

    ushort* us  = (ushort*)d_ws;
    ushort* Khi = us;                   // 1048576
    ushort* Klo = us + 1048576;
    ushort* VtS = us + 2097152;
    ushort* Qhi = us + 3145728;
    ushort* Qlo = us + 3407872;
    ushort* xh  = us + 3670016;
    ushort* xl  = us + 3932160;
    ushort* Wqh = us + 4194304;
    ushort* Wql = us + 4456448;
    ushort* Wkh = us + 4718592;
    ushort* Wkl = us + 4980736;
    ushort* Wvh = us + 5242880;
    ushort* Wvl = us + 5505024;
    ushort* Woh = us + 5767168;
    ushort* Wol = us + 6029312;
    ushort* Aoh = us + 6291456;
    ushort* Aol = us + 6553600;         // ends 6815744 us (13.6 MB)
    uint* gflags = (uint*)(us + 8388608);   // 3*256 flags at byte 16 MB
    uint* grel   = gflags + 768;            // 3 release words

    fused_all<<<dim3(256), dim3(512), 0, stream>>>(
        x, kc, vc, Wq, bq, Wk, bk, Wv, bv, Wo, bo, out,
        Khi, Klo, VtS, Qhi, Qlo, xh, xl,
        Wqh, Wql, Wkh, Wkl, Wvh, Wvl, Woh, Wol,
        Aoh, Aol, gflags, grel);
}

// Round 9
// 159.989 us; speedup vs baseline: 3.0546x; 3.0546x over previous
//
#include <hip/hip_runtime.h>
#include <math.h>

// Problem constants
#define B_   2
#define LTOT   8192
#define LCACHE 6144
#define LNEW   2048

#define QSCALE (0.125f * 1.44269504088896f)   // 1/sqrt(64) * log2(e)

typedef __attribute__((ext_vector_type(8))) short bf16x8;
typedef __attribute__((ext_vector_type(4))) float f32x4;

__device__ __forceinline__ ushort f2bf(float f) {             // RTN f32->bf16
    unsigned u = __float_as_uint(f);
    return (ushort)((u + 0x7fffu + ((u >> 16) & 1u)) >> 16);
}
__device__ __forceinline__ void split_hilo(float v, ushort& h, ushort& l) {
    h = f2bf(v);
    l = f2bf(v - __uint_as_float((unsigned)h << 16));
}

// ---------------------------------------------------------------------------
// Layouts (identical to round 6, all verified):
// GEMM frag: flat = R*8192 + kk*512 + lane*8 + j
//            holds T[row=R*16+(lane&15)][col=kk*32+(lane>>4)*8+j]
// K swz:     flat = T*2048 + st*1024 + h*512 + lane*8 + j
//            holds K[key=T*32+st*4+(lr&3)+(lr>>2)*8][e=h*32+lg*8+j]
// V^T swz:   flat = T*2048 + dt*512 + lane*8 + j
//            holds V[key=T*32+lg*8+j][d=dt*16+lr]
// ---------------------------------------------------------------------------

__device__ __forceinline__ void convert_slot(
    const float* __restrict__ src, ushort* __restrict__ dh, ushort* __restrict__ dl, int slot)
{
    const int R = slot >> 10, kk = (slot >> 6) & 15, ln = slot & 63;
    const int row = R * 16 + (ln & 15), col = kk * 32 + (ln >> 4) * 8;
    const float4 a  = *reinterpret_cast<const float4*>(src + row * 512 + col);
    const float4 b4 = *reinterpret_cast<const float4*>(src + row * 512 + col + 4);
    ushort4 h0, l0, h1, l1;
    split_hilo(a.x,  h0.x, l0.x); split_hilo(a.y,  h0.y, l0.y);
    split_hilo(a.z,  h0.z, l0.z); split_hilo(a.w,  h0.w, l0.w);
    split_hilo(b4.x, h1.x, l1.x); split_hilo(b4.y, h1.y, l1.y);
    split_hilo(b4.z, h1.z, l1.z); split_hilo(b4.w, h1.w, l1.w);
    *reinterpret_cast<ushort4*>(dh + slot * 8)     = h0;
    *reinterpret_cast<ushort4*>(dh + slot * 8 + 4) = h1;
    *reinterpret_cast<ushort4*>(dl + slot * 8)     = l0;
    *reinterpret_cast<ushort4*>(dl + slot * 8 + 4) = l1;
}

__device__ __forceinline__ void kcache_slot(
    const float* __restrict__ Kc, ushort* __restrict__ Khi, ushort* __restrict__ Klo,
    int b, int slot)
{
    const int key = slot >> 3, g = slot & 7;
    const int h = g >> 2, lg = g & 3;
    const float* src = Kc + ((size_t)b * LCACHE + key) * 64 + g * 8;
    const float4 a  = *reinterpret_cast<const float4*>(src);
    const float4 b4 = *reinterpret_cast<const float4*>(src + 4);
    const int T = key >> 5, r = key & 31;
    const int lr = ((r >> 3) << 2) | (r & 3), st = (r >> 2) & 1;
    const size_t dst = (size_t)b * 524288 + T * 2048 + st * 1024
                     + h * 512 + (((size_t)lg << 4 | lr)) * 8;
    ushort4 h0, l0, h1, l1;
    split_hilo(a.x,  h0.x, l0.x); split_hilo(a.y,  h0.y, l0.y);
    split_hilo(a.z,  h0.z, l0.z); split_hilo(a.w,  h0.w, l0.w);
    split_hilo(b4.x, h1.x, l1.x); split_hilo(b4.y, h1.y, l1.y);
    split_hilo(b4.z, h1.z, l1.z); split_hilo(b4.w, h1.w, l1.w);
    *reinterpret_cast<ushort4*>(Khi + dst)     = h0;
    *reinterpret_cast<ushort4*>(Khi + dst + 4) = h1;
    *reinterpret_cast<ushort4*>(Klo + dst)     = l0;
    *reinterpret_cast<ushort4*>(Klo + dst + 4) = l1;
}

// 8-wave MFMA NT GEMM tile: 64x64 block tile, wave stripe 16(m) x 32(n).
__device__ __forceinline__ void proj8(
    const ushort* __restrict__ AhF, const ushort* __restrict__ AlF,
    const ushort* __restrict__ BhF, const ushort* __restrict__ BlF,
    const float* __restrict__ bias, const int mode, const int bxp, const int byp,
    ushort* __restrict__ d1, ushort* __restrict__ d2, float* __restrict__ df)
{
    const int tid = threadIdx.x;
    const int wv = tid >> 6, lane = tid & 63;
    const int lr = lane & 15, lg = lane >> 4;
    const int m0 = byp * 64 + (wv & 3) * 16;   // token stripe
    const int n0 = bxp * 64 + (wv >> 2) * 32;  // output-dim half
    const int mT = m0 >> 4, nT = n0 >> 4;

    f32x4 acc[2];
    acc[0] = (f32x4){0.f, 0.f, 0.f, 0.f};
    acc[1] = (f32x4){0.f, 0.f, 0.f, 0.f};

    const ushort* Ah = AhF + (size_t)nT * 8192 + lane * 8;
    const ushort* Al = AlF + (size_t)nT * 8192 + lane * 8;
    const ushort* Bh = BhF + (size_t)mT * 8192 + lane * 8;
    const ushort* Bl = BlF + (size_t)mT * 8192 + lane * 8;

#pragma unroll 4
    for (int kk = 0; kk < 16; ++kk) {
        bf16x8 ah[2], al[2], bh, bl;
#pragma unroll
        for (int t = 0; t < 2; ++t) {
            ah[t] = *reinterpret_cast<const bf16x8*>(Ah + t * 8192 + kk * 512);
            al[t] = *reinterpret_cast<const bf16x8*>(Al + t * 8192 + kk * 512);
        }
        bh = *reinterpret_cast<const bf16x8*>(Bh + kk * 512);
        bl = *reinterpret_cast<const bf16x8*>(Bl + kk * 512);
        __builtin_amdgcn_s_setprio(1);
#pragma unroll
        for (int ni = 0; ni < 2; ++ni) {
            acc[ni] = __builtin_amdgcn_mfma_f32_16x16x32_bf16(ah[ni], bh, acc[ni], 0, 0, 0);
            acc[ni] = __builtin_amdgcn_mfma_f32_16x16x32_bf16(ah[ni], bl, acc[ni], 0, 0, 0);
            acc[ni] = __builtin_amdgcn_mfma_f32_16x16x32_bf16(al[ni], bh, acc[ni], 0, 0, 0);
        }
        __builtin_amdgcn_s_setprio(0);
    }

#pragma unroll
    for (int ni = 0; ni < 2; ++ni) {
        const int tok = m0 + lr;
        const int e   = n0 + ni * 16 + lg * 4;
        const float4 bb4 = *reinterpret_cast<const float4*>(&bias[e]);
        float v0 = acc[ni].x + bb4.x, v1 = acc[ni].y + bb4.y;
        float v2 = acc[ni].z + bb4.z, v3 = acc[ni].w + bb4.w;
        const int bb = tok >> 8, s = tok & 255;
        if (mode == 0) {
            v0 *= QSCALE; v1 *= QSCALE; v2 *= QSCALE; v3 *= QSCALE;
            ushort4 h, l;
            split_hilo(v0, h.x, l.x); split_hilo(v1, h.y, l.y);
            split_hilo(v2, h.z, l.z); split_hilo(v3, h.w, l.w);
            const size_t off = (size_t)bb * 131072 + s * 512 + e;
            *reinterpret_cast<ushort4*>(d1 + off) = h;
            *reinterpret_cast<ushort4*>(d2 + off) = l;
        } else if (mode == 1) {
            const int key = LCACHE + s * 8 + (e >> 6);
            const int d0 = e & 63;
            const int T = key >> 5, r = key & 31;
            const int klr = ((r >> 3) << 2) | (r & 3), st = (r >> 2) & 1;
            const int h = d0 >> 5, lg2 = (d0 >> 3) & 3, j0 = d0 & 7;
            const size_t dst = (size_t)bb * 524288 + T * 2048 + st * 1024
                             + h * 512 + ((lg2 << 4) | klr) * 8 + j0;
            ushort4 hh, ll;
            split_hilo(v0, hh.x, ll.x); split_hilo(v1, hh.y, ll.y);
            split_hilo(v2, hh.z, ll.z); split_hilo(v3, hh.w, ll.w);
            *reinterpret_cast<ushort4*>(d1 + dst) = hh;
            *reinterpret_cast<ushort4*>(d2 + dst) = ll;
        } else if (mode == 2) {
            const int key = LCACHE + s * 8 + (e >> 6);
            const int Tv = key >> 5;
            const int lg3 = (key & 31) >> 3, j = key & 7;
            const float vals[4] = {v0, v1, v2, v3};
#pragma unroll
            for (int c = 0; c < 4; ++c) {
                const int d = (e & 63) + c;
                const int dt = d >> 4, vlr = d & 15;
                d1[(size_t)bb * 524288 + Tv * 2048 + dt * 512
                   + ((lg3 << 4) | vlr) * 8 + j] = f2bf(vals[c]);
            }
        } else {
            float4 o; o.x = v0; o.y = v1; o.z = v2; o.w = v3;
            *reinterpret_cast<float4*>(df + (size_t)tok * 512 + e) = o;
        }
    }
}

// attention macros: r6 swizzled ALOAD, r4-verified single-(m,l) COMPUTE
#define ALOAD(kf, lf, vf, t) do {                                                   \
    _Pragma("unroll")                                                               \
    for (int st = 0; st < 2; ++st) {                                                \
        _Pragma("unroll")                                                           \
        for (int h = 0; h < 2; ++h) {                                               \
            kf[st][h] = *reinterpret_cast<const bf16x8*>(kh_p + (t) * 2048 + st * 1024 + h * 512); \
            lf[st][h] = *reinterpret_cast<const bf16x8*>(kl_p + (t) * 2048 + st * 1024 + h * 512); \
        }                                                                           \
    }                                                                               \
    _Pragma("unroll")                                                               \
    for (int dt = 0; dt < 4; ++dt)                                                  \
        vf[dt] = *reinterpret_cast<const bf16x8*>(vt_p + (t) * 2048 + dt * 512);    \
} while (0)

#define ACOMP(kf, lf, vf) do {                                                      \
    f32x4 s0 = {0.f,0.f,0.f,0.f}, s1 = {0.f,0.f,0.f,0.f};                           \
    __builtin_amdgcn_s_setprio(1);                                                  \
    _Pragma("unroll")                                                               \
    for (int h = 0; h < 2; ++h) {                                                   \
        s0 = __builtin_amdgcn_mfma_f32_16x16x32_bf16(kf[0][h], qh[h], s0, 0, 0, 0); \
        s0 = __builtin_amdgcn_mfma_f32_16x16x32_bf16(kf[0][h], ql[h], s0, 0, 0, 0); \
        s0 = __builtin_amdgcn_mfma_f32_16x16x32_bf16(lf[0][h], qh[h], s0, 0, 0, 0); \
        s1 = __builtin_amdgcn_mfma_f32_16x16x32_bf16(kf[1][h], qh[h], s1, 0, 0, 0); \
        s1 = __builtin_amdgcn_mfma_f32_16x16x32_bf16(kf[1][h], ql[h], s1, 0, 0, 0); \
        s1 = __builtin_amdgcn_mfma_f32_16x16x32_bf16(lf[1][h], qh[h], s1, 0, 0, 0); \
    }                                                                               \
    __builtin_amdgcn_s_setprio(0);                                                  \
    float tm = fmaxf(fmaxf(fmaxf(s0.x, s0.y), fmaxf(s0.z, s0.w)),                   \
                     fmaxf(fmaxf(s1.x, s1.y), fmaxf(s1.z, s1.w)));                  \
    tm = fmaxf(tm, __shfl_xor(tm, 16));                                             \
    tm = fmaxf(tm, __shfl_xor(tm, 32));                                             \
    const float mn = fmaxf(m, tm);                                                  \
    const float corr = __builtin_exp2f(m - mn);                                     \
    float p[8];                                                                     \
    p[0] = __builtin_exp2f(s0.x - mn); p[1] = __builtin_exp2f(s0.y - mn);           \
    p[2] = __builtin_exp2f(s0.z - mn); p[3] = __builtin_exp2f(s0.w - mn);           \
    p[4] = __builtin_exp2f(s1.x - mn); p[5] = __builtin_exp2f(s1.y - mn);           \
    p[6] = __builtin_exp2f(s1.z - mn); p[7] = __builtin_exp2f(s1.w - mn);           \
    float ps = ((p[0]+p[1]) + (p[2]+p[3])) + ((p[4]+p[5]) + (p[6]+p[7]));           \
    ps += __shfl_xor(ps, 16);                                                       \
    ps += __shfl_xor(ps, 32);                                                       \
    l = l * corr + ps; m = mn;                                                      \
    union { bf16x8 v; ushort u[8]; } pf;                                            \
    _Pragma("unroll")                                                               \
    for (int j = 0; j < 8; ++j) pf.u[j] = f2bf(p[j]);                               \
    __builtin_amdgcn_s_setprio(1);                                                  \
    _Pragma("unroll")                                                               \
    for (int dt = 0; dt < 4; ++dt) {                                                \
        f32x4 a = acc[dt];                                                          \
        a.x *= corr; a.y *= corr; a.z *= corr; a.w *= corr;                         \
        acc[dt] = __builtin_amdgcn_mfma_f32_16x16x32_bf16(vf[dt], pf.v, a, 0, 0, 0);\
    }                                                                               \
    __builtin_amdgcn_s_setprio(0);                                                  \
} while (0)

// ---------------------------------------------------------------------------
// Software grid barrier v2 (cost-model-aware):
//  - ONE release store per block (single buffer_wbl2: flushes phase writes)
//  - RELAXED polls (agent atomic loads hit L3 directly; NO buffer_inv in loop)
//  - ONE acquire load per block after release observed (single buffer_inv)
// ws is re-poisoned 0xAA each launch so magic epochs never collide.
// ---------------------------------------------------------------------------
__device__ __forceinline__ void gridbarrier(uint* flags, uint* rel, int bar, int bid)
{
    __syncthreads();                      // all waves' writes drained to L2
    const uint ep = 0x1357A001u + (uint)bar;
    uint* f = flags + bar * 256;
    if (threadIdx.x == 0)                 // one wbl2 + flag store per block
        __hip_atomic_store(f + bid, ep, __ATOMIC_RELEASE, __HIP_MEMORY_SCOPE_AGENT);
    if (bid == 0) {
        if (threadIdx.x < 256) {
            while (__hip_atomic_load(f + threadIdx.x, __ATOMIC_RELAXED,
                                     __HIP_MEMORY_SCOPE_AGENT) != ep)
                __builtin_amdgcn_s_sleep(32);
        }
        __syncthreads();
        if (threadIdx.x == 0)
            __hip_atomic_store(rel + bar, ep, __ATOMIC_RELEASE, __HIP_MEMORY_SCOPE_AGENT);
    }
    if (threadIdx.x == 0) {
        while (__hip_atomic_load(rel + bar, __ATOMIC_RELAXED,
                                 __HIP_MEMORY_SCOPE_AGENT) != ep)
            __builtin_amdgcn_s_sleep(32);
        // one buffer_inv per block: discard possibly-stale L1/L2 lines
        (void)__hip_atomic_load(f + bid, __ATOMIC_ACQUIRE, __HIP_MEMORY_SCOPE_AGENT);
    }
    __syncthreads();
}

// ---------------------------------------------------------------------------
// fused_all: 256 blocks x 512 threads (8 waves), plain launch.
// P1 prep -> P2 proj_qkv -> P3 attn (full-L, writes Ao) -> P4 proj_o.
// ---------------------------------------------------------------------------
__global__ __launch_bounds__(512, 2) void fused_all(
    const float* __restrict__ x,  const float* __restrict__ Kc,
    const float* __restrict__ Vc,
    const float* __restrict__ Wq, const float* __restrict__ bq,
    const float* __restrict__ Wk, const float* __restrict__ bk,
    const float* __restrict__ Wv, const float* __restrict__ bv,
    const float* __restrict__ Wo, const float* __restrict__ bo,
    float* __restrict__ out,
    ushort* __restrict__ Khi, ushort* __restrict__ Klo, ushort* __restrict__ VtS,
    ushort* __restrict__ Qhi, ushort* __restrict__ Qlo,
    ushort* __restrict__ xh,  ushort* __restrict__ xl,
    ushort* __restrict__ Wqh, ushort* __restrict__ Wql,
    ushort* __restrict__ Wkh, ushort* __restrict__ Wkl,
    ushort* __restrict__ Wvh, ushort* __restrict__ Wvl,
    ushort* __restrict__ Woh, ushort* __restrict__ Wol,
    ushort* __restrict__ Aoh, ushort* __restrict__ Aol,
    uint* __restrict__ gflags, uint* __restrict__ grel)
{
    __shared__ union SM {
        ushort sT[64][68];
        struct { float sAcc[8][16][68]; float sM[8][16]; float sL[8][16]; } a;
    } sm;

    const int bid = blockIdx.x, tid = threadIdx.x;
    const int gid = bid * 512 + tid;            // 0..131071

    // ---------------- P1: prep ---------------------------------------------
    {
        {   // (a) {x,Wq,Wk,Wv}: one slot/thread; Wo: gid<32768
            const int z = gid >> 15, slot = gid & 32767;
            const float* src; ushort* dh; ushort* dl;
            if (z == 0)      { src = x;  dh = xh;  dl = xl;  }
            else if (z == 1) { src = Wq; dh = Wqh; dl = Wql; }
            else if (z == 2) { src = Wk; dh = Wkh; dl = Wkl; }
            else             { src = Wv; dh = Wvh; dl = Wvl; }
            convert_slot(src, dh, dl, slot);
            if (gid < 32768) convert_slot(Wo, Woh, Wol, gid);
        }
        // (b) K cache: 98304 slots
        if (gid < 98304) {
            const int b = gid >= 49152 ? 1 : 0;
            kcache_slot(Kc, Khi, Klo, b, gid - b * 49152);
        }
        // (c) V cache: 192 tiles of 64 keys, blocks 0..191
        if (bid < 192) {
            const int b = bid / 96, kt = bid % 96;
            const int key0 = kt * 64;
#pragma unroll
            for (int it = 0; it < 2; ++it) {
                const int id = it * 512 + tid;              // 0..1023
                const int row = id >> 4, c4 = (id & 15) << 2;
                const float4 v = *reinterpret_cast<const float4*>(
                    &Vc[((size_t)b * LCACHE + key0 + row) * 64 + c4]);
                sm.sT[c4+0][row] = f2bf(v.x); sm.sT[c4+1][row] = f2bf(v.y);
                sm.sT[c4+2][row] = f2bf(v.z); sm.sT[c4+3][row] = f2bf(v.w);
            }
            __syncthreads();
            {
                const int s = tid;                          // 0..511
                const int Tl = s >> 8, dt = (s >> 6) & 3, ln = s & 63;
                const int lr2 = ln & 15, lg2 = ln >> 4;
                const int kb = Tl * 32 + lg2 * 8;
                ushort4 o0, o1;
                o0.x = sm.sT[dt*16+lr2][kb+0]; o0.y = sm.sT[dt*16+lr2][kb+1];
                o0.z = sm.sT[dt*16+lr2][kb+2]; o0.w = sm.sT[dt*16+lr2][kb+3];
                o1.x = sm.sT[dt*16+lr2][kb+4]; o1.y = sm.sT[dt*16+lr2][kb+5];
                o1.z = sm.sT[dt*16+lr2][kb+6]; o1.w = sm.sT[dt*16+lr2][kb+7];
                const size_t dst = (size_t)b * 524288 + ((key0 >> 5) + Tl) * 2048
                                 + dt * 512 + ln * 8;
                *reinterpret_cast<ushort4*>(VtS + dst)     = o0;
                *reinterpret_cast<ushort4*>(VtS + dst + 4) = o1;
            }
        }
    }
    gridbarrier(gflags, grel, 0, bid);

    // ---------------- P2: QKV projections (blocks 0..191) ------------------
    if (bid < 192) {
        const int z = bid >> 6, idx = bid & 63;
        const int bxp = idx & 7, byp = idx >> 3;
        if (z == 0)      proj8(Wqh, Wql, xh, xl, bq, 0, bxp, byp, Qhi, Qlo, nullptr);
        else if (z == 1) proj8(Wkh, Wkl, xh, xl, bk, 1, bxp, byp, Khi, Klo, nullptr);
        else             proj8(Wvh, Wvl, xh, xl, bv, 2, bxp, byp, VtS, nullptr, nullptr);
    }
    gridbarrier(gflags, grel, 1, bid);

    // ---------------- P3: attn, full L per block, writes Ao -----------------
    {
        const int wv = tid >> 6, lane = tid & 63;
        const int lr = lane & 15, lg = lane >> 4;
        const int qb = bid & 127, b = bid >> 7;   // 16 q-rows/block

        bf16x8 qh[2], ql[2];
        {
            const int qrow0 = b * 2048 + qb * 16 + lr;
#pragma unroll
            for (int h = 0; h < 2; ++h) {
                const int off = qrow0 * 64 + h * 32 + lg * 8;
                qh[h] = *reinterpret_cast<const bf16x8*>(Qhi + off);
                ql[h] = *reinterpret_cast<const bf16x8*>(Qlo + off);
            }
        }

        const int T0 = wv * 32;                   // 32 tiles of 32 keys/wave
        const ushort* kh_p = Khi + (size_t)b * 524288 + (size_t)T0 * 2048 + lane * 8;
        const ushort* kl_p = Klo + (size_t)b * 524288 + (size_t)T0 * 2048 + lane * 8;
        const ushort* vt_p = VtS + (size_t)b * 524288 + (size_t)T0 * 2048 + lane * 8;

        f32x4 acc[4];
#pragma unroll
        for (int dt = 0; dt < 4; ++dt) acc[dt] = (f32x4){0.f, 0.f, 0.f, 0.f};
        float m = -INFINITY, l = 0.f;

        bf16x8 kfA[2][2], lfA[2][2], vfA[4];
        bf16x8 kfB[2][2], lfB[2][2], vfB[4];

        ALOAD(kfA, lfA, vfA, 0);
        for (int tt = 0; tt < 16; ++tt) {         // 32 tiles, 2 per iter
            ALOAD(kfB, lfB, vfB, 2 * tt + 1);
            ACOMP(kfA, lfA, vfA);
            if (tt < 15) ALOAD(kfA, lfA, vfA, 2 * tt + 2);
            ACOMP(kfB, lfB, vfB);
        }

        // per-wave partials -> LDS (C/D: col=lane&15 -> qrow, rows -> dims)
#pragma unroll
        for (int dt = 0; dt < 4; ++dt) {
            float4 o; o.x = acc[dt].x; o.y = acc[dt].y; o.z = acc[dt].z; o.w = acc[dt].w;
            *reinterpret_cast<float4*>(&sm.a.sAcc[wv][lr][dt * 16 + lg * 4]) = o;
        }
        if (lg == 0) { sm.a.sM[wv][lr] = m; sm.a.sL[wv][lr] = l; }
        __syncthreads();

        // merge 8 waves; write Ao (GEMM-frag hi/lo) directly
        {
            const int row = tid >> 5, d0 = (tid & 31) * 2;
            float ms = -INFINITY;
#pragma unroll
            for (int w = 0; w < 8; ++w) ms = fmaxf(ms, sm.a.sM[w][row]);
            float den = 0.f, n0 = 0.f, n1 = 0.f;
#pragma unroll
            for (int w = 0; w < 8; ++w) {
                const float e = __builtin_exp2f(sm.a.sM[w][row] - ms);
                den = fmaf(sm.a.sL[w][row], e, den);
                const float2 a = *reinterpret_cast<const float2*>(&sm.a.sAcc[w][row][d0]);
                n0 = fmaf(a.x, e, n0);
                n1 = fmaf(a.y, e, n1);
            }
            const float inv = 1.0f / den;
            const float v0 = n0 * inv, v1 = n1 * inv;
            const int row_g = b * 2048 + qb * 16 + row;
            const int qr = row_g & 2047;
            const int tok = b * 256 + (qr >> 3);
            const int e_  = (qr & 7) * 64 + d0;
            const int R = tok >> 4, lrr = tok & 15, kk = e_ >> 5, lgg = (e_ >> 3) & 3;
            const size_t dst = (size_t)R * 8192 + kk * 512 + ((lgg << 4) | lrr) * 8 + (d0 & 7);
            ushort h0, l0u, h1, l1u;
            split_hilo(v0, h0, l0u); split_hilo(v1, h1, l1u);
            ushort2 ho; ho.x = h0; ho.y = h1;
            ushort2 lo; lo.x = l0u; lo.y = l1u;
            *reinterpret_cast<ushort2*>(Aoh + dst) = ho;
            *reinterpret_cast<ushort2*>(Aol + dst) = lo;
        }
    }
    gridbarrier(gflags, grel, 2, bid);

    // ---------------- P4: output projection (blocks 0..63) ------------------
    if (bid < 64) {
        const int bxp = bid & 7, byp = bid >> 3;
        proj8(Woh, Wol, Aoh, Aol, bo, 3, bxp, byp, nullptr, nullptr, out);
    }
}

// ---------------------------------------------------------------------------
extern "C" void kernel_launch(void* const* d_in, const int* in_sizes, int n_in,
                              void* d_out, int out_size, void* d_ws, size_t ws_size,
                              hipStream_t stream)
{
    const float* x  = (const float*)d_in[0];
    const float* kc = (const float*)d_in[1];
    const float* vc = (const float*)d_in[2];
    const float* Wq = (const float*)d_in[3];
    const float* bq = (const float*)d_in[4];
    const float* Wk = (const float*)d_in[5];
    const float* bk = (const float*)d_in[6];
    const float* Wv = (const float*)d_in[7];
    const float* bv = (const float*)d_in[8];
    const float* Wo = (const float*)d_in[9];
    const float* bo = (const float*)d_in[10];
    float* out = (float*)d_out;

    ushort* us  = (ushort*)d_ws;
    ushort* Khi = us;                   // 1048576
    ushort* Klo = us + 1048576;
    ushort* VtS = us + 2097152;
    ushort* Qhi = us + 3145728;
    ushort* Qlo = us + 3407872;
    ushort* xh  = us + 3670016;
    ushort* xl  = us + 3932160;
    ushort* Wqh = us + 4194304;
    ushort* Wql = us + 4456448;
    ushort* Wkh = us + 4718592;
    ushort* Wkl = us + 4980736;
    ushort* Wvh = us + 5242880;
    ushort* Wvl = us + 5505024;
    ushort* Woh = us + 5767168;
    ushort* Wol = us + 6029312;
    ushort* Aoh = us + 6291456;
    ushort* Aol = us + 6553600;         // ends 6815744 us (13.6 MB)
    uint* gflags = (uint*)(us + 8388608);   // 3*256 flags at byte 16 MB
    uint* grel   = gflags + 768;            // 3 release words

    fused_all<<<dim3(256), dim3(512), 0, stream>>>(
        x, kc, vc, Wq, bq, Wk, bk, Wv, bv, Wo, bo, out,
        Khi, Klo, VtS, Qhi, Qlo, xh, xl,
        Wqh, Wql, Wkh, Wkl, Wvh, Wvl, Woh, Wol,
        Aoh, Aol, gflags, grel);
}

// Round 10
// 157.960 us; speedup vs baseline: 3.0938x; 1.0128x over previous
//
#include <hip/hip_runtime.h>
#include <math.h>

// Problem constants
#define B_   2
#define LTOT   8192
#define LCACHE 6144
#define LNEW   2048

#define QSCALE (0.125f * 1.44269504088896f)   // 1/sqrt(64) * log2(e)

typedef __attribute__((ext_vector_type(8))) short bf16x8;
typedef __attribute__((ext_vector_type(4))) float f32x4;

__device__ __forceinline__ ushort f2bf(float f) {             // RTN f32->bf16
    unsigned u = __float_as_uint(f);
    return (ushort)((u + 0x7fffu + ((u >> 16) & 1u)) >> 16);
}
__device__ __forceinline__ void split_hilo(float v, ushort& h, ushort& l) {
    h = f2bf(v);
    l = f2bf(v - __uint_as_float((unsigned)h << 16));
}

// ---------------------------------------------------------------------------
// Layouts (identical to round 6, all verified):
// GEMM frag: flat = R*8192 + kk*512 + lane*8 + j
//            holds T[row=R*16+(lane&15)][col=kk*32+(lane>>4)*8+j]
// K swz:     flat = T*2048 + st*1024 + h*512 + lane*8 + j
//            holds K[key=T*32+st*4+(lr&3)+(lr>>2)*8][e=h*32+lg*8+j]
// V^T swz:   flat = T*2048 + dt*512 + lane*8 + j
//            holds V[key=T*32+lg*8+j][d=dt*16+lr]
// ---------------------------------------------------------------------------

__device__ __forceinline__ void convert_slot(
    const float* __restrict__ src, ushort* __restrict__ dh, ushort* __restrict__ dl, int slot)
{
    const int R = slot >> 10, kk = (slot >> 6) & 15, ln = slot & 63;
    const int row = R * 16 + (ln & 15), col = kk * 32 + (ln >> 4) * 8;
    const float4 a  = *reinterpret_cast<const float4*>(src + row * 512 + col);
    const float4 b4 = *reinterpret_cast<const float4*>(src + row * 512 + col + 4);
    ushort4 h0, l0, h1, l1;
    split_hilo(a.x,  h0.x, l0.x); split_hilo(a.y,  h0.y, l0.y);
    split_hilo(a.z,  h0.z, l0.z); split_hilo(a.w,  h0.w, l0.w);
    split_hilo(b4.x, h1.x, l1.x); split_hilo(b4.y, h1.y, l1.y);
    split_hilo(b4.z, h1.z, l1.z); split_hilo(b4.w, h1.w, l1.w);
    *reinterpret_cast<ushort4*>(dh + slot * 8)     = h0;
    *reinterpret_cast<ushort4*>(dh + slot * 8 + 4) = h1;
    *reinterpret_cast<ushort4*>(dl + slot * 8)     = l0;
    *reinterpret_cast<ushort4*>(dl + slot * 8 + 4) = l1;
}

__device__ __forceinline__ void kcache_slot(
    const float* __restrict__ Kc, ushort* __restrict__ Khi, ushort* __restrict__ Klo,
    int b, int slot)
{
    const int key = slot >> 3, g = slot & 7;
    const int h = g >> 2, lg = g & 3;
    const float* src = Kc + ((size_t)b * LCACHE + key) * 64 + g * 8;
    const float4 a  = *reinterpret_cast<const float4*>(src);
    const float4 b4 = *reinterpret_cast<const float4*>(src + 4);
    const int T = key >> 5, r = key & 31;
    const int lr = ((r >> 3) << 2) | (r & 3), st = (r >> 2) & 1;
    const size_t dst = (size_t)b * 524288 + T * 2048 + st * 1024
                     + h * 512 + (((size_t)lg << 4 | lr)) * 8;
    ushort4 h0, l0, h1, l1;
    split_hilo(a.x,  h0.x, l0.x); split_hilo(a.y,  h0.y, l0.y);
    split_hilo(a.z,  h0.z, l0.z); split_hilo(a.w,  h0.w, l0.w);
    split_hilo(b4.x, h1.x, l1.x); split_hilo(b4.y, h1.y, l1.y);
    split_hilo(b4.z, h1.z, l1.z); split_hilo(b4.w, h1.w, l1.w);
    *reinterpret_cast<ushort4*>(Khi + dst)     = h0;
    *reinterpret_cast<ushort4*>(Khi + dst + 4) = h1;
    *reinterpret_cast<ushort4*>(Klo + dst)     = l0;
    *reinterpret_cast<ushort4*>(Klo + dst + 4) = l1;
}

// 8-wave MFMA NT GEMM tile: 64x64 block tile, wave stripe 16(m) x 32(n).
__device__ __forceinline__ void proj8(
    const ushort* __restrict__ AhF, const ushort* __restrict__ AlF,
    const ushort* __restrict__ BhF, const ushort* __restrict__ BlF,
    const float* __restrict__ bias, const int mode, const int bxp, const int byp,
    ushort* __restrict__ d1, ushort* __restrict__ d2, float* __restrict__ df)
{
    const int tid = threadIdx.x;
    const int wv = tid >> 6, lane = tid & 63;
    const int lr = lane & 15, lg = lane >> 4;
    const int m0 = byp * 64 + (wv & 3) * 16;   // token stripe
    const int n0 = bxp * 64 + (wv >> 2) * 32;  // output-dim half
    const int mT = m0 >> 4, nT = n0 >> 4;

    f32x4 acc[2];
    acc[0] = (f32x4){0.f, 0.f, 0.f, 0.f};
    acc[1] = (f32x4){0.f, 0.f, 0.f, 0.f};

    const ushort* Ah = AhF + (size_t)nT * 8192 + lane * 8;
    const ushort* Al = AlF + (size_t)nT * 8192 + lane * 8;
    const ushort* Bh = BhF + (size_t)mT * 8192 + lane * 8;
    const ushort* Bl = BlF + (size_t)mT * 8192 + lane * 8;

#pragma unroll 4
    for (int kk = 0; kk < 16; ++kk) {
        bf16x8 ah[2], al[2], bh, bl;
#pragma unroll
        for (int t = 0; t < 2; ++t) {
            ah[t] = *reinterpret_cast<const bf16x8*>(Ah + t * 8192 + kk * 512);
            al[t] = *reinterpret_cast<const bf16x8*>(Al + t * 8192 + kk * 512);
        }
        bh = *reinterpret_cast<const bf16x8*>(Bh + kk * 512);
        bl = *reinterpret_cast<const bf16x8*>(Bl + kk * 512);
        __builtin_amdgcn_s_setprio(1);
#pragma unroll
        for (int ni = 0; ni < 2; ++ni) {
            acc[ni] = __builtin_amdgcn_mfma_f32_16x16x32_bf16(ah[ni], bh, acc[ni], 0, 0, 0);
            acc[ni] = __builtin_amdgcn_mfma_f32_16x16x32_bf16(ah[ni], bl, acc[ni], 0, 0, 0);
            acc[ni] = __builtin_amdgcn_mfma_f32_16x16x32_bf16(al[ni], bh, acc[ni], 0, 0, 0);
        }
        __builtin_amdgcn_s_setprio(0);
    }

#pragma unroll
    for (int ni = 0; ni < 2; ++ni) {
        const int tok = m0 + lr;
        const int e   = n0 + ni * 16 + lg * 4;
        const float4 bb4 = *reinterpret_cast<const float4*>(&bias[e]);
        float v0 = acc[ni].x + bb4.x, v1 = acc[ni].y + bb4.y;
        float v2 = acc[ni].z + bb4.z, v3 = acc[ni].w + bb4.w;
        const int bb = tok >> 8, s = tok & 255;
        if (mode == 0) {
            v0 *= QSCALE; v1 *= QSCALE; v2 *= QSCALE; v3 *= QSCALE;
            ushort4 h, l;
            split_hilo(v0, h.x, l.x); split_hilo(v1, h.y, l.y);
            split_hilo(v2, h.z, l.z); split_hilo(v3, h.w, l.w);
            const size_t off = (size_t)bb * 131072 + s * 512 + e;
            *reinterpret_cast<ushort4*>(d1 + off) = h;
            *reinterpret_cast<ushort4*>(d2 + off) = l;
        } else if (mode == 1) {
            const int key = LCACHE + s * 8 + (e >> 6);
            const int d0 = e & 63;
            const int T = key >> 5, r = key & 31;
            const int klr = ((r >> 3) << 2) | (r & 3), st = (r >> 2) & 1;
            const int h = d0 >> 5, lg2 = (d0 >> 3) & 3, j0 = d0 & 7;
            const size_t dst = (size_t)bb * 524288 + T * 2048 + st * 1024
                             + h * 512 + ((lg2 << 4) | klr) * 8 + j0;
            ushort4 hh, ll;
            split_hilo(v0, hh.x, ll.x); split_hilo(v1, hh.y, ll.y);
            split_hilo(v2, hh.z, ll.z); split_hilo(v3, hh.w, ll.w);
            *reinterpret_cast<ushort4*>(d1 + dst) = hh;
            *reinterpret_cast<ushort4*>(d2 + dst) = ll;
        } else if (mode == 2) {
            const int key = LCACHE + s * 8 + (e >> 6);
            const int Tv = key >> 5;
            const int lg3 = (key & 31) >> 3, j = key & 7;
            const float vals[4] = {v0, v1, v2, v3};
#pragma unroll
            for (int c = 0; c < 4; ++c) {
                const int d = (e & 63) + c;
                const int dt = d >> 4, vlr = d & 15;
                d1[(size_t)bb * 524288 + Tv * 2048 + dt * 512
                   + ((lg3 << 4) | vlr) * 8 + j] = f2bf(vals[c]);
            }
        } else {
            float4 o; o.x = v0; o.y = v1; o.z = v2; o.w = v3;
            *reinterpret_cast<float4*>(df + (size_t)tok * 512 + e) = o;
        }
    }
}

// attention macros: r6 swizzled ALOAD, r4-verified single-(m,l) COMPUTE
#define ALOAD(kf, lf, vf, t) do {                                                   \
    _Pragma("unroll")                                                               \
    for (int st = 0; st < 2; ++st) {                                                \
        _Pragma("unroll")                                                           \
        for (int h = 0; h < 2; ++h) {                                               \
            kf[st][h] = *reinterpret_cast<const bf16x8*>(kh_p + (t) * 2048 + st * 1024 + h * 512); \
            lf[st][h] = *reinterpret_cast<const bf16x8*>(kl_p + (t) * 2048 + st * 1024 + h * 512); \
        }                                                                           \
    }                                                                               \
    _Pragma("unroll")                                                               \
    for (int dt = 0; dt < 4; ++dt)                                                  \
        vf[dt] = *reinterpret_cast<const bf16x8*>(vt_p + (t) * 2048 + dt * 512);    \
} while (0)

#define ACOMP(kf, lf, vf) do {                                                      \
    f32x4 s0 = {0.f,0.f,0.f,0.f}, s1 = {0.f,0.f,0.f,0.f};                           \
    __builtin_amdgcn_s_setprio(1);                                                  \
    _Pragma("unroll")                                                               \
    for (int h = 0; h < 2; ++h) {                                                   \
        s0 = __builtin_amdgcn_mfma_f32_16x16x32_bf16(kf[0][h], qh[h], s0, 0, 0, 0); \
        s0 = __builtin_amdgcn_mfma_f32_16x16x32_bf16(kf[0][h], ql[h], s0, 0, 0, 0); \
        s0 = __builtin_amdgcn_mfma_f32_16x16x32_bf16(lf[0][h], qh[h], s0, 0, 0, 0); \
        s1 = __builtin_amdgcn_mfma_f32_16x16x32_bf16(kf[1][h], qh[h], s1, 0, 0, 0); \
        s1 = __builtin_amdgcn_mfma_f32_16x16x32_bf16(kf[1][h], ql[h], s1, 0, 0, 0); \
        s1 = __builtin_amdgcn_mfma_f32_16x16x32_bf16(lf[1][h], qh[h], s1, 0, 0, 0); \
    }                                                                               \
    __builtin_amdgcn_s_setprio(0);                                                  \
    float tm = fmaxf(fmaxf(fmaxf(s0.x, s0.y), fmaxf(s0.z, s0.w)),                   \
                     fmaxf(fmaxf(s1.x, s1.y), fmaxf(s1.z, s1.w)));                  \
    tm = fmaxf(tm, __shfl_xor(tm, 16));                                             \
    tm = fmaxf(tm, __shfl_xor(tm, 32));                                             \
    const float mn = fmaxf(m, tm);                                                  \
    const float corr = __builtin_exp2f(m - mn);                                     \
    float p[8];                                                                     \
    p[0] = __builtin_exp2f(s0.x - mn); p[1] = __builtin_exp2f(s0.y - mn);           \
    p[2] = __builtin_exp2f(s0.z - mn); p[3] = __builtin_exp2f(s0.w - mn);           \
    p[4] = __builtin_exp2f(s1.x - mn); p[5] = __builtin_exp2f(s1.y - mn);           \
    p[6] = __builtin_exp2f(s1.z - mn); p[7] = __builtin_exp2f(s1.w - mn);           \
    float ps = ((p[0]+p[1]) + (p[2]+p[3])) + ((p[4]+p[5]) + (p[6]+p[7]));           \
    ps += __shfl_xor(ps, 16);                                                       \
    ps += __shfl_xor(ps, 32);                                                       \
    l = l * corr + ps; m = mn;                                                      \
    union { bf16x8 v; ushort u[8]; } pf;                                            \
    _Pragma("unroll")                                                               \
    for (int j = 0; j < 8; ++j) pf.u[j] = f2bf(p[j]);                               \
    __builtin_amdgcn_s_setprio(1);                                                  \
    _Pragma("unroll")                                                               \
    for (int dt = 0; dt < 4; ++dt) {                                                \
        f32x4 a = acc[dt];                                                          \
        a.x *= corr; a.y *= corr; a.z *= corr; a.w *= corr;                         \
        acc[dt] = __builtin_amdgcn_mfma_f32_16x16x32_bf16(vf[dt], pf.v, a, 0, 0, 0);\
    }                                                                               \
    __builtin_amdgcn_s_setprio(0);                                                  \
} while (0)

// ---------------------------------------------------------------------------
// Software grid barrier v2 (unchanged from round 9 — measured OK):
// one release store / relaxed polls / one acquire per block.
// ---------------------------------------------------------------------------
__device__ __forceinline__ void gridbarrier(uint* flags, uint* rel, int bar, int bid)
{
    __syncthreads();
    const uint ep = 0x1357A001u + (uint)bar;
    uint* f = flags + bar * 256;
    if (threadIdx.x == 0)
        __hip_atomic_store(f + bid, ep, __ATOMIC_RELEASE, __HIP_MEMORY_SCOPE_AGENT);
    if (bid == 0) {
        if (threadIdx.x < 256) {
            while (__hip_atomic_load(f + threadIdx.x, __ATOMIC_RELAXED,
                                     __HIP_MEMORY_SCOPE_AGENT) != ep)
                __builtin_amdgcn_s_sleep(32);
        }
        __syncthreads();
        if (threadIdx.x == 0)
            __hip_atomic_store(rel + bar, ep, __ATOMIC_RELEASE, __HIP_MEMORY_SCOPE_AGENT);
    }
    if (threadIdx.x == 0) {
        while (__hip_atomic_load(rel + bar, __ATOMIC_RELAXED,
                                 __HIP_MEMORY_SCOPE_AGENT) != ep)
            __builtin_amdgcn_s_sleep(32);
        (void)__hip_atomic_load(f + bid, __ATOMIC_ACQUIRE, __HIP_MEMORY_SCOPE_AGENT);
    }
    __syncthreads();
}

// ---------------------------------------------------------------------------
// fused_all: 256 blocks x 512 threads (8 waves), plain launch.
// P1 convert x/Wq/Wk/Wv -> P2 proj_qkv (192 blk) || Wo+Kcache+Vcache (64 blk)
// -> P3 attn (XCD-local KV, writes Ao) -> P4 proj_o.
// ---------------------------------------------------------------------------
__global__ __launch_bounds__(512, 2) void fused_all(
    const float* __restrict__ x,  const float* __restrict__ Kc,
    const float* __restrict__ Vc,
    const float* __restrict__ Wq, const float* __restrict__ bq,
    const float* __restrict__ Wk, const float* __restrict__ bk,
    const float* __restrict__ Wv, const float* __restrict__ bv,
    const float* __restrict__ Wo, const float* __restrict__ bo,
    float* __restrict__ out,
    ushort* __restrict__ Khi, ushort* __restrict__ Klo, ushort* __restrict__ VtS,
    ushort* __restrict__ Qhi, ushort* __restrict__ Qlo,
    ushort* __restrict__ xh,  ushort* __restrict__ xl,
    ushort* __restrict__ Wqh, ushort* __restrict__ Wql,
    ushort* __restrict__ Wkh, ushort* __restrict__ Wkl,
    ushort* __restrict__ Wvh, ushort* __restrict__ Wvl,
    ushort* __restrict__ Woh, ushort* __restrict__ Wol,
    ushort* __restrict__ Aoh, ushort* __restrict__ Aol,
    uint* __restrict__ gflags, uint* __restrict__ grel)
{
    __shared__ union SM {
        ushort sT[64][68];
        struct { float sAcc[8][16][68]; float sM[8][16]; float sL[8][16]; } a;
    } sm;

    const int bid = blockIdx.x, tid = threadIdx.x;
    const int gid = bid * 512 + tid;            // 0..131071

    // ---------------- P1: convert x, Wq, Wk, Wv (one slot/thread) ----------
    {
        const int z = gid >> 15, slot = gid & 32767;
        const float* src; ushort* dh; ushort* dl;
        if (z == 0)      { src = x;  dh = xh;  dl = xl;  }
        else if (z == 1) { src = Wq; dh = Wqh; dl = Wql; }
        else if (z == 2) { src = Wk; dh = Wkh; dl = Wkl; }
        else             { src = Wv; dh = Wvh; dl = Wvl; }
        convert_slot(src, dh, dl, slot);
    }
    gridbarrier(gflags, grel, 0, bid);

    // ---------------- P2: proj_qkv (0..191) || prep tail (192..255) --------
    if (bid < 192) {
        const int z = bid >> 6, idx = bid & 63;
        const int bxp = idx & 7, byp = idx >> 3;
        if (z == 0)      proj8(Wqh, Wql, xh, xl, bq, 0, bxp, byp, Qhi, Qlo, nullptr);
        else if (z == 1) proj8(Wkh, Wkl, xh, xl, bk, 1, bxp, byp, Khi, Klo, nullptr);
        else             proj8(Wvh, Wvl, xh, xl, bv, 2, bxp, byp, VtS, nullptr, nullptr);
    } else {
        const int lid = (bid - 192) * 512 + tid;            // 0..32767
        // (a) Wo conversion: 32768 slots
        convert_slot(Wo, Woh, Wol, lid);
        // (b) K cache: 98304 slots, 3 per thread
#pragma unroll
        for (int k = 0; k < 3; ++k) {
            int slot = lid + k * 32768;
            const int b = slot >= 49152 ? 1 : 0;
            kcache_slot(Kc, Khi, Klo, b, slot - b * 49152);
        }
        // (c) V cache: 192 tiles over 64 blocks = 3 tiles/block (LDS transpose)
#pragma unroll
        for (int vt = 0; vt < 3; ++vt) {
            const int tix = (bid - 192) * 3 + vt;           // 0..191
            const int b = tix / 96, kt = tix % 96;
            const int key0 = kt * 64;
            __syncthreads();
#pragma unroll
            for (int it = 0; it < 2; ++it) {
                const int id = it * 512 + tid;              // 0..1023
                const int row = id >> 4, c4 = (id & 15) << 2;
                const float4 v = *reinterpret_cast<const float4*>(
                    &Vc[((size_t)b * LCACHE + key0 + row) * 64 + c4]);
                sm.sT[c4+0][row] = f2bf(v.x); sm.sT[c4+1][row] = f2bf(v.y);
                sm.sT[c4+2][row] = f2bf(v.z); sm.sT[c4+3][row] = f2bf(v.w);
            }
            __syncthreads();
            {
                const int s = tid;                          // 0..511
                const int Tl = s >> 8, dt = (s >> 6) & 3, ln = s & 63;
                const int lr2 = ln & 15, lg2 = ln >> 4;
                const int kb = Tl * 32 + lg2 * 8;
                ushort4 o0, o1;
                o0.x = sm.sT[dt*16+lr2][kb+0]; o0.y = sm.sT[dt*16+lr2][kb+1];
                o0.z = sm.sT[dt*16+lr2][kb+2]; o0.w = sm.sT[dt*16+lr2][kb+3];
                o1.x = sm.sT[dt*16+lr2][kb+4]; o1.y = sm.sT[dt*16+lr2][kb+5];
                o1.z = sm.sT[dt*16+lr2][kb+6]; o1.w = sm.sT[dt*16+lr2][kb+7];
                const size_t dst = (size_t)b * 524288 + ((key0 >> 5) + Tl) * 2048
                                 + dt * 512 + ln * 8;
                *reinterpret_cast<ushort4*>(VtS + dst)     = o0;
                *reinterpret_cast<ushort4*>(VtS + dst + 4) = o1;
            }
        }
    }
    gridbarrier(gflags, grel, 1, bid);

    // ---------------- P3: attn, XCD-local KV, writes Ao ---------------------
    {
        const int wv = tid >> 6, lane = tid & 63;
        const int lr = lane & 15, lg = lane >> 4;
        // XCD-aware mapping: bid%8 = XCD (round-robin dispatch). XCDs 0-3 ->
        // batch 0, XCDs 4-7 -> batch 1, so each XCD's L2 holds ONE batch's KV.
        const int xcd = bid & 7;
        const int b = xcd >> 2;
        const int qb = (bid >> 3) * 4 + (xcd & 3);          // 0..127

        bf16x8 qh[2], ql[2];
        {
            const int qrow0 = b * 2048 + qb * 16 + lr;
#pragma unroll
            for (int h = 0; h < 2; ++h) {
                const int off = qrow0 * 64 + h * 32 + lg * 8;
                qh[h] = *reinterpret_cast<const bf16x8*>(Qhi + off);
                ql[h] = *reinterpret_cast<const bf16x8*>(Qlo + off);
            }
        }

        const int T0 = wv * 32;                   // 32 tiles of 32 keys/wave
        const ushort* kh_p = Khi + (size_t)b * 524288 + (size_t)T0 * 2048 + lane * 8;
        const ushort* kl_p = Klo + (size_t)b * 524288 + (size_t)T0 * 2048 + lane * 8;
        const ushort* vt_p = VtS + (size_t)b * 524288 + (size_t)T0 * 2048 + lane * 8;

        f32x4 acc[4];
#pragma unroll
        for (int dt = 0; dt < 4; ++dt) acc[dt] = (f32x4){0.f, 0.f, 0.f, 0.f};
        float m = -INFINITY, l = 0.f;

        bf16x8 kfA[2][2], lfA[2][2], vfA[4];
        bf16x8 kfB[2][2], lfB[2][2], vfB[4];

        ALOAD(kfA, lfA, vfA, 0);
        for (int tt = 0; tt < 16; ++tt) {         // 32 tiles, 2 per iter
            ALOAD(kfB, lfB, vfB, 2 * tt + 1);
            ACOMP(kfA, lfA, vfA);
            if (tt < 15) ALOAD(kfA, lfA, vfA, 2 * tt + 2);
            ACOMP(kfB, lfB, vfB);
        }

        // per-wave partials -> LDS (C/D: col=lane&15 -> qrow, rows -> dims)
        __syncthreads();
#pragma unroll
        for (int dt = 0; dt < 4; ++dt) {
            float4 o; o.x = acc[dt].x; o.y = acc[dt].y; o.z = acc[dt].z; o.w = acc[dt].w;
            *reinterpret_cast<float4*>(&sm.a.sAcc[wv][lr][dt * 16 + lg * 4]) = o;
        }
        if (lg == 0) { sm.a.sM[wv][lr] = m; sm.a.sL[wv][lr] = l; }
        __syncthreads();

        // merge 8 waves; write Ao (GEMM-frag hi/lo) directly
        {
            const int row = tid >> 5, d0 = (tid & 31) * 2;
            float ms = -INFINITY;
#pragma unroll
            for (int w = 0; w < 8; ++w) ms = fmaxf(ms, sm.a.sM[w][row]);
            float den = 0.f, n0 = 0.f, n1 = 0.f;
#pragma unroll
            for (int w = 0; w < 8; ++w) {
                const float e = __builtin_exp2f(sm.a.sM[w][row] - ms);
                den = fmaf(sm.a.sL[w][row], e, den);
                const float2 a = *reinterpret_cast<const float2*>(&sm.a.sAcc[w][row][d0]);
                n0 = fmaf(a.x, e, n0);
                n1 = fmaf(a.y, e, n1);
            }
            const float inv = 1.0f / den;
            const float v0 = n0 * inv, v1 = n1 * inv;
            const int row_g = b * 2048 + qb * 16 + row;
            const int qr = row_g & 2047;
            const int tok = b * 256 + (qr >> 3);
            const int e_  = (qr & 7) * 64 + d0;
            const int R = tok >> 4, lrr = tok & 15, kk = e_ >> 5, lgg = (e_ >> 3) & 3;
            const size_t dst = (size_t)R * 8192 + kk * 512 + ((lgg << 4) | lrr) * 8 + (d0 & 7);
            ushort h0, l0u, h1, l1u;
            split_hilo(v0, h0, l0u); split_hilo(v1, h1, l1u);
            ushort2 ho; ho.x = h0; ho.y = h1;
            ushort2 lo; lo.x = l0u; lo.y = l1u;
            *reinterpret_cast<ushort2*>(Aoh + dst) = ho;
            *reinterpret_cast<ushort2*>(Aol + dst) = lo;
        }
    }
    gridbarrier(gflags, grel, 2, bid);

    // ---------------- P4: output projection (blocks 0..63) ------------------
    if (bid < 64) {
        const int bxp = bid & 7, byp = bid >> 3;
        proj8(Woh, Wol, Aoh, Aol, bo, 3, bxp, byp, nullptr, nullptr, out);
    }
}

// ---------------------------------------------------------------------------
extern "C" void kernel_launch(void* const* d_in, const int* in_sizes, int n_in,
                              void* d_out, int out_size, void* d_ws, size_t ws_size,
                              hipStream_t stream)
{
    const float* x  = (const float*)d_in[0];
    const float* kc = (const float*)d_in[1];
    const float* vc = (const float*)d_in[2];
    const float* Wq = (const float*)d_in[3];
    const float* bq = (const float*)d_in[4];
    const float* Wk = (const float*)d_in[5];
    const float* bk = (const float*)d_in[6];
    const float* Wv = (const float*)d_in[7];
    const float* bv = (const float*)d_in[8];
    const float* Wo = (const float*)d_in[9];
    const float* bo = (const float*)d_in[10];
    float* out = (float*)d_out;

    ushort* us  = (ushort*)d_ws;
    ushort* Khi = us;                   // 1048576
    ushort* Klo = us + 1048576;
    ushort* VtS = us + 2097152;
    ushort* Qhi = us + 3145728;
    ushort* Qlo = us + 3407872;
    ushort* xh  = us + 3670016;
    ushort* xl  = us + 3932160;
    ushort* Wqh = us + 4194304;
    ushort* Wql = us + 4456448;
    ushort* Wkh = us + 4718592;
    ushort* Wkl = us + 4980736;
    ushort* Wvh = us + 5242880;
    ushort* Wvl = us + 5505024;
    ushort* Woh = us + 5767168;
    ushort* Wol = us + 6029312;
    ushort* Aoh = us + 6291456;
    ushort* Aol = us + 6553600;         // ends 6815744 us (13.6 MB)
    uint* gflags = (uint*)(us + 8388608);   // 3*256 flags at byte 16 MB
    uint* grel   = gflags + 768;            // 3 release words

    fused_all<<<dim3(256), dim3(512), 0, stream>>>(
        x, kc, vc, Wq, bq, Wk, bk, Wv, bv, Wo, bo, out,
        Khi, Klo, VtS, Qhi, Qlo, xh, xl,
        Wqh, Wql, Wkh, Wkl, Wvh, Wvl, Woh, Wol,
        Aoh, Aol, gflags, grel);
}